// Round 11
// baseline (1703.762 us; speedup 1.0000x reference)
//
#include <hip/hip_runtime.h>

#define NN 262144
#define HH 128
#define EE 16
#define MAXD 12
#define CAP 8192          // per-(depth,category) capacity; expected ~5041
#define CLR 16            // cap: left+right children per slot per depth
#define CH 8              // cap: head children per slot per depth
#define RR 4              // rows per MLP block (4 -> ~1260 blocks, ~5 waves/SIMD)
#define G_GATHER 640      // S1: blocks [0,G_GATHER) gather, rest lep MLP

struct Prm {
    const float* x_in;
    const int*   parents;
    const int*   depths;
    const int*   states;
    const float* pef;
    const float* plef;
    const float *mW1, *mb1, *mW2, *mb2;
    const float *pW1, *pb1, *pW2, *pb2;
    const float *eW1, *eb1, *eW2, *eb2;
    float* x;
    // zeroed-per-launch:
    int *cntB;            // [36]
    int *cntCLR, *cntCH;  // [12*CAP] each
    int *maskL, *maskH;   // [NN] bit d: has left/head child at depth d
    // memset 0x7f per launch:
    int *firstL, *firstH; // [12*NN] min list-position of p's child (the "slot")
    // rebuilt each launch before use:
    int *listL, *listR, *listHd;       // [12*CAP]
    int *childLR, *childH;             // [12*CAP*CLR], [12*CAP*CH]
    float *left_c, *right_c, *lepOut;  // [CAP*HH]
};

// ---------------------------------------------------------------------------
// x copy through the COMPUTE path (L2-coherent).
__global__ __launch_bounds__(256)
void copy_x(const float4* __restrict__ src, float4* __restrict__ dst) {
    int i = blockIdx.x * 256 + threadIdx.x;
    const int gsz = 2048 * 256;
    #pragma unroll 4
    for (; i < NN * HH / 4; i += gsz) dst[i] = src[i];
}

// ---------------------------------------------------------------------------
// setup A: bucket nodes by (depth, cat), build masks, min-position slot
// assignment (scattered atomicMin — no hot counter lines).
__global__ __launch_bounds__(128)
void setupA(Prm prm) {
    __shared__ int lcnt[36], lbase[36];
    const int tid = threadIdx.x;
    const int gtid = blockIdx.x * 128 + tid;       // == node id (2048*128 = NN)

    if (tid < 36) lcnt[tid] = 0;
    __syncthreads();
    int dep = prm.depths[gtid], st = prm.states[gtid];
    int b = -1, rank = 0, p = 0;
    if (dep >= 1 && (st == 0 || st == 1 || st == 3)) {
        int cat = (st == 3) ? 2 : st;
        b = (dep - 1) * 3 + cat;
        rank = atomicAdd(&lcnt[b], 1);
        p = prm.parents[gtid];
        if (cat == 0)      atomicOr(&prm.maskL[p], 1 << dep);
        else if (cat == 2) atomicOr(&prm.maskH[p], 1 << dep);
    }
    __syncthreads();
    if (tid < 36 && lcnt[tid] > 0) lbase[tid] = atomicAdd(&prm.cntB[tid], lcnt[tid]);
    __syncthreads();
    if (b >= 0) {
        int idx = lbase[b] + rank;
        if (idx < CAP) {
            int dd = b / 3, cat = b - dd * 3;
            if (cat == 0) {
                prm.listL[dd * CAP + idx] = gtid;
                atomicMin(&prm.firstL[(size_t)dd * NN + p], idx);   // slot = min pos
            } else if (cat == 1) {
                prm.listR[dd * CAP + idx] = gtid;
            } else {
                prm.listHd[dd * CAP + idx] = gtid;
                atomicMin(&prm.firstH[(size_t)dd * NN + p], idx);
            }
        }
    }
}

// ---------------------------------------------------------------------------
// setup C: append children to per-slot lists (scattered atomics only)
__global__ __launch_bounds__(256)
void setupC(Prm prm) {
    for (int t = blockIdx.x * 256 + threadIdx.x; t < 12 * CAP; t += gridDim.x * 256) {
        int dd = t / CAP, g = t - dd * CAP;
        int d1 = dd + 1;
        if (g < min(prm.cntB[dd * 3 + 0], CAP)) {            // lefts (tag 0)
            int c = prm.listL[dd * CAP + g];
            int s = prm.firstL[(size_t)dd * NN + prm.parents[c]];
            int idx = atomicAdd(&prm.cntCLR[dd * CAP + s], 1);
            if (idx < CLR) prm.childLR[(size_t)(dd * CAP + s) * CLR + idx] = c * 2;
        }
        if (g < min(prm.cntB[dd * 3 + 1], CAP)) {            // rights (tag 1)
            int c = prm.listR[dd * CAP + g];
            int p = prm.parents[c];
            if ((prm.maskL[p] >> d1) & 1) {                  // only if parent has a left
                int s = prm.firstL[(size_t)dd * NN + p];
                int idx = atomicAdd(&prm.cntCLR[dd * CAP + s], 1);
                if (idx < CLR) prm.childLR[(size_t)(dd * CAP + s) * CLR + idx] = c * 2 + 1;
            }
        }
        if (g < min(prm.cntB[dd * 3 + 2], CAP)) {            // heads: store POSITION g
            int c = prm.listHd[dd * CAP + g];
            int s = prm.firstH[(size_t)dd * NN + prm.parents[c]];
            int idx = atomicAdd(&prm.cntCH[dd * CAP + s], 1);
            if (idx < CH) prm.childH[(size_t)(dd * CAP + s) * CH + idx] = g;
        }
    }
}

// ---------------------------------------------------------------------------
// RR-row 2-layer MLP, 128 threads (thread j = output column j).
// MODE 0 merger: rows=listL, ONLY canonical row g==firstL[p] writes x[p]
// MODE 1 lep:    rows=listHd -> lepOut[g]
// MODE 2 lem:    rows=listHd, ONLY canonical row g==firstH[p] writes x[p]
//                (single-writer: kills the dup-row read/write race on x[p])
template <int MODE, int INDIM>
__device__ void mlpR(const Prm& prm, int d, int g0, int n,
                     const int* __restrict__ rowList,
                     const float* __restrict__ W1, const float* __restrict__ b1,
                     const float* __restrict__ W2, const float* __restrict__ b2,
                     float* sh_raw) {
    const int tid = threadIdx.x;
    float (*sh_in)[INDIM] = (float (*)[INDIM])sh_raw;
    float (*sh_h)[HH]     = (float (*)[HH])(sh_raw + RR * INDIM);
    const int dd = d - 1;
    bool vld[RR];

    if (MODE == 0) {
        #pragma unroll
        for (int r = 0; r < RR; ++r) {
            int g = g0 + r;
            float lv = 0.f, rv = 0.f, pv = 0.f;
            vld[r] = false;
            if (g < n) {
                int p = prm.parents[rowList[g]];
                int s = prm.firstL[(size_t)dd * NN + p];
                vld[r] = (g == s);                       // canonical duplicate only
                lv = prm.left_c [(size_t)s * HH + tid];
                rv = prm.right_c[(size_t)s * HH + tid];
                if (tid < EE) pv = prm.pef[(size_t)p * EE + tid];
            }
            sh_in[r][tid] = lv;
            sh_in[r][HH + tid] = rv;
            if (tid < EE) sh_in[r][2 * HH + tid] = pv;
        }
    } else if (MODE == 2) {
        #pragma unroll
        for (int r = 0; r < RR; ++r) {
            int g = g0 + r;
            float xv = 0.f, mh = 0.f;
            vld[r] = false;
            if (g < n) {
                int p = prm.parents[rowList[g]];
                int s = prm.firstH[(size_t)dd * NN + p];
                vld[r] = (g == s);                       // canonical duplicate only
                xv = prm.x[(size_t)p * HH + tid];
                int cb = dd * CAP + s;
                int cnt = prm.cntCH[cb];
                if (cnt > CH) cnt = CH;
                for (int i = 0; i < cnt; ++i) {
                    int pos = prm.childH[(size_t)cb * CH + i];
                    mh += prm.lepOut[(size_t)pos * HH + tid];
                }
            }
            sh_in[r][tid] = xv;
            sh_in[r][HH + tid] = mh;
        }
    } else {
        #pragma unroll
        for (int r = 0; r < RR; ++r) vld[r] = (g0 + r) < n;
        for (int idx = tid; idx < RR * INDIM; idx += 128) {
            int r = idx / INDIM, k = idx - r * INDIM;
            int g = g0 + r;
            float v = 0.f;
            if (g < n) {
                int c = rowList[g];
                if (k < HH) v = prm.x[(size_t)c * HH + k];
                else        v = prm.plef[(size_t)c * EE + (k - HH)];
            }
            sh_in[r][k] = v;
        }
    }
    __syncthreads();

    float acc[RR];
    #pragma unroll
    for (int r = 0; r < RR; ++r) acc[r] = 0.f;
    for (int kk = 0; kk < INDIM; kk += 4) {
        float w0 = W1[(size_t)(kk + 0) * HH + tid];
        float w1 = W1[(size_t)(kk + 1) * HH + tid];
        float w2 = W1[(size_t)(kk + 2) * HH + tid];
        float w3 = W1[(size_t)(kk + 3) * HH + tid];
        #pragma unroll
        for (int r = 0; r < RR; ++r) {
            float4 v = *(const float4*)&sh_in[r][kk];
            acc[r] += v.x * w0 + v.y * w1 + v.z * w2 + v.w * w3;
        }
    }
    float bb = b1[tid];
    #pragma unroll
    for (int r = 0; r < RR; ++r) sh_h[r][tid] = fmaxf(acc[r] + bb, 0.f);
    __syncthreads();

    float acc2[RR];
    #pragma unroll
    for (int r = 0; r < RR; ++r) acc2[r] = 0.f;
    for (int kk = 0; kk < HH; kk += 4) {
        float w0 = W2[(size_t)(kk + 0) * HH + tid];
        float w1 = W2[(size_t)(kk + 1) * HH + tid];
        float w2 = W2[(size_t)(kk + 2) * HH + tid];
        float w3 = W2[(size_t)(kk + 3) * HH + tid];
        #pragma unroll
        for (int r = 0; r < RR; ++r) {
            float4 v = *(const float4*)&sh_h[r][kk];
            acc2[r] += v.x * w0 + v.y * w1 + v.z * w2 + v.w * w3;
        }
    }
    float bb2 = b2[tid];
    for (int r = 0; r < RR; ++r) {
        int g = g0 + r;
        if (g >= n) break;
        if (!vld[r]) continue;
        float val = acc2[r] + bb2;
        if (MODE == 0) {
            prm.x[(size_t)prm.parents[rowList[g]] * HH + tid] = val;
        } else if (MODE == 1) {
            prm.lepOut[(size_t)g * HH + tid] = val;
        } else {
            int p = prm.parents[rowList[g]];
            if (!((prm.maskL[p] >> d) & 1))        // parents_mask priority
                prm.x[(size_t)p * HH + tid] = val;
        }
    }
}

// ---------------------------------------------------------------------------
// S1 (reads x only): gather left/right child sums [0,G_GATHER) || lep MLP rest
__global__ __launch_bounds__(128)
void s1_kernel(Prm prm, int d) {
    const int dd = d - 1;
    const int bid = blockIdx.x, tid = threadIdx.x;
    if (bid < G_GATHER) {
        int nL = min(prm.cntB[dd * 3 + 0], CAP);
        int w = tid >> 6, lane = tid & 63;
        for (int s = bid * 2 + w; s < nL; s += G_GATHER * 2) {
            int cb = dd * CAP + s;
            int cnt = prm.cntCLR[cb];
            if (cnt > CLR) cnt = CLR;
            float l0 = 0.f, l1 = 0.f, r0 = 0.f, r1 = 0.f;
            for (int i = 0; i < cnt; ++i) {
                int e = prm.childLR[(size_t)cb * CLR + i];
                const float2 v = *(const float2*)(prm.x + (size_t)(e >> 1) * HH + lane * 2);
                if (e & 1) { r0 += v.x; r1 += v.y; } else { l0 += v.x; l1 += v.y; }
            }
            *(float2*)(prm.left_c  + (size_t)s * HH + lane * 2) = make_float2(l0, l1);
            *(float2*)(prm.right_c + (size_t)s * HH + lane * 2) = make_float2(r0, r1);
        }
    } else {
        __shared__ float sh_raw[RR * (HH + EE) + RR * HH];
        int nH = min(prm.cntB[dd * 3 + 2], CAP);
        int g0 = (bid - G_GATHER) * RR;
        if (g0 < nH)
            mlpR<1, HH + EE>(prm, d, g0, nH, prm.listHd + dd * CAP,
                             prm.pW1, prm.pb1, prm.pW2, prm.pb2, sh_raw);
    }
}

// ---------------------------------------------------------------------------
// S2 (writes x): merger [0,CAP/RR) || lem [CAP/RR, 2*CAP/RR).
// Single-writer per x row (canonical dup only); lem's x-read races only on
// rows whose output is discarded.
__global__ __launch_bounds__(128)
void s2_kernel(Prm prm, int d) {
    const int dd = d - 1;
    const int bid = blockIdx.x;
    __shared__ float sh_raw[RR * (2 * HH + EE) + RR * HH];
    if (bid < CAP / RR) {
        int nL = min(prm.cntB[dd * 3 + 0], CAP);
        int g0 = bid * RR;
        if (g0 < nL)
            mlpR<0, 2 * HH + EE>(prm, d, g0, nL, prm.listL + dd * CAP,
                                 prm.mW1, prm.mb1, prm.mW2, prm.mb2, sh_raw);
    } else {
        int nH = min(prm.cntB[dd * 3 + 2], CAP);
        int g0 = (bid - CAP / RR) * RR;
        if (g0 < nH)
            mlpR<2, 2 * HH>(prm, d, g0, nH, prm.listHd + dd * CAP,
                            prm.eW1, prm.eb1, prm.eW2, prm.eb2, sh_raw);
    }
}

// ---------------------------------------------------------------------------
extern "C" void kernel_launch(void* const* d_in, const int* in_sizes, int n_in,
                              void* d_out, int out_size, void* d_ws, size_t ws_size,
                              hipStream_t stream) {
    Prm prm;
    prm.x_in    = (const float*)d_in[0];
    const int* edge = (const int*)d_in[1];
    prm.depths  = (const int*)d_in[2];
    prm.states  = (const int*)d_in[3];
    prm.pef     = (const float*)d_in[4];
    prm.plef    = (const float*)d_in[5];
    prm.mW1 = (const float*)d_in[6];  prm.mb1 = (const float*)d_in[7];
    prm.mW2 = (const float*)d_in[8];  prm.mb2 = (const float*)d_in[9];
    prm.pW1 = (const float*)d_in[10]; prm.pb1 = (const float*)d_in[11];
    prm.pW2 = (const float*)d_in[12]; prm.pb2 = (const float*)d_in[13];
    prm.eW1 = (const float*)d_in[14]; prm.eb1 = (const float*)d_in[15];
    prm.eW2 = (const float*)d_in[16]; prm.eb2 = (const float*)d_in[17];
    prm.x = (float*)d_out;
    prm.parents = edge + NN;

    char* w = (char*)d_ws;
    auto alloc = [&](size_t bytes) {
        void* p = (void*)w;
        w += (bytes + 255) & ~(size_t)255;
        return p;
    };
    // ---- zeroed region ----
    char* zbase = w;
    prm.cntB   = (int*)alloc(64 * 4);
    prm.cntCLR = (int*)alloc((size_t)12 * CAP * 4);
    prm.cntCH  = (int*)alloc((size_t)12 * CAP * 4);
    prm.maskL  = (int*)alloc((size_t)NN * 4);
    prm.maskH  = (int*)alloc((size_t)NN * 4);
    size_t zbytes = (size_t)(w - zbase);
    // ---- 0x7f region (atomicMin init) ----
    char* fbase = w;
    prm.firstL = (int*)alloc((size_t)12 * NN * 4);
    prm.firstH = (int*)alloc((size_t)12 * NN * 4);
    size_t fbytes = (size_t)(w - fbase);
    // ---- non-zeroed (fully rebuilt before use each launch) ----
    prm.listL     = (int*)alloc((size_t)12 * CAP * 4);
    prm.listR     = (int*)alloc((size_t)12 * CAP * 4);
    prm.listHd    = (int*)alloc((size_t)12 * CAP * 4);
    prm.childLR   = (int*)alloc((size_t)12 * CAP * CLR * 4);
    prm.childH    = (int*)alloc((size_t)12 * CAP * CH * 4);
    prm.left_c    = (float*)alloc((size_t)CAP * HH * 4);
    prm.right_c   = (float*)alloc((size_t)CAP * HH * 4);
    prm.lepOut    = (float*)alloc((size_t)CAP * HH * 4);

    hipMemsetAsync(zbase, 0, zbytes, stream);
    hipMemsetAsync(fbase, 0x7f, fbytes, stream);   // firstL/firstH = huge

    copy_x<<<2048, 256, 0, stream>>>((const float4*)prm.x_in, (float4*)prm.x);
    setupA<<<NN / 128, 128, 0, stream>>>(prm);
    setupC<<<384, 256, 0, stream>>>(prm);

    for (int d = MAXD; d >= 1; --d) {
        s1_kernel<<<G_GATHER + CAP / RR, 128, 0, stream>>>(prm, d);
        s2_kernel<<<2 * (CAP / RR), 128, 0, stream>>>(prm, d);
    }
}

// Round 12
// 1035.837 us; speedup vs baseline: 1.6448x; 1.6448x over previous
//
#include <hip/hip_runtime.h>

#define NN 262144
#define HH 128
#define EE 16
#define MAXD 12
#define CAP 8192          // per-(depth,category) capacity; expected ~5041
#define CLR 16            // cap: left+right children per slot per depth
#define CH 8              // cap: head children per slot per depth
#define RR 8              // rows per MLP block (8 -> FMA:load ratio 8, VGPR<=128 via launch_bounds)
#define G_GATHER 640      // S1: blocks [0,G_GATHER) gather, rest lep MLP

struct Prm {
    const float* x_in;
    const int*   parents;
    const int*   depths;
    const int*   states;
    const float* pef;
    const float* plef;
    const float *mW1, *mb1, *mW2, *mb2;
    const float *pW1, *pb1, *pW2, *pb2;
    const float *eW1, *eb1, *eW2, *eb2;
    float* x;
    // zeroed-per-launch:
    int *cntB;            // [36]
    int *cntCLR, *cntCH;  // [12*CAP] each
    int *maskL, *maskH;   // [NN] bit d: has left/head child at depth d
    // memset 0x7f per launch:
    int *firstL, *firstH; // [12*NN] min list-position of p's child (the "slot")
    // rebuilt each launch before use:
    int *listL, *listR, *listHd;       // [12*CAP]
    int *childLR, *childH;             // [12*CAP*CLR], [12*CAP*CH]
    float *left_c, *right_c, *lepOut;  // [CAP*HH]
};

// ---------------------------------------------------------------------------
// x copy through the COMPUTE path (L2-coherent; SDMA memcpy caused R9's stale-
// line failure).
__global__ __launch_bounds__(256)
void copy_x(const float4* __restrict__ src, float4* __restrict__ dst) {
    int i = blockIdx.x * 256 + threadIdx.x;
    const int gsz = 2048 * 256;
    #pragma unroll 4
    for (; i < NN * HH / 4; i += gsz) dst[i] = src[i];
}

// ---------------------------------------------------------------------------
// setup A: bucket nodes by (depth, cat), build masks, min-position slot
// assignment (scattered atomicMin — no hot counter lines).
__global__ __launch_bounds__(128)
void setupA(Prm prm) {
    __shared__ int lcnt[36], lbase[36];
    const int tid = threadIdx.x;
    const int gtid = blockIdx.x * 128 + tid;       // == node id (2048*128 = NN)

    if (tid < 36) lcnt[tid] = 0;
    __syncthreads();
    int dep = prm.depths[gtid], st = prm.states[gtid];
    int b = -1, rank = 0, p = 0;
    if (dep >= 1 && (st == 0 || st == 1 || st == 3)) {
        int cat = (st == 3) ? 2 : st;
        b = (dep - 1) * 3 + cat;
        rank = atomicAdd(&lcnt[b], 1);
        p = prm.parents[gtid];
        if (cat == 0)      atomicOr(&prm.maskL[p], 1 << dep);
        else if (cat == 2) atomicOr(&prm.maskH[p], 1 << dep);
    }
    __syncthreads();
    if (tid < 36 && lcnt[tid] > 0) lbase[tid] = atomicAdd(&prm.cntB[tid], lcnt[tid]);
    __syncthreads();
    if (b >= 0) {
        int idx = lbase[b] + rank;
        if (idx < CAP) {
            int dd = b / 3, cat = b - dd * 3;
            if (cat == 0) {
                prm.listL[dd * CAP + idx] = gtid;
                atomicMin(&prm.firstL[(size_t)dd * NN + p], idx);   // slot = min pos
            } else if (cat == 1) {
                prm.listR[dd * CAP + idx] = gtid;
            } else {
                prm.listHd[dd * CAP + idx] = gtid;
                atomicMin(&prm.firstH[(size_t)dd * NN + p], idx);
            }
        }
    }
}

// ---------------------------------------------------------------------------
// setup C: append children to per-slot lists (scattered atomics only)
__global__ __launch_bounds__(256)
void setupC(Prm prm) {
    for (int t = blockIdx.x * 256 + threadIdx.x; t < 12 * CAP; t += gridDim.x * 256) {
        int dd = t / CAP, g = t - dd * CAP;
        int d1 = dd + 1;
        if (g < min(prm.cntB[dd * 3 + 0], CAP)) {            // lefts (tag 0)
            int c = prm.listL[dd * CAP + g];
            int s = prm.firstL[(size_t)dd * NN + prm.parents[c]];
            int idx = atomicAdd(&prm.cntCLR[dd * CAP + s], 1);
            if (idx < CLR) prm.childLR[(size_t)(dd * CAP + s) * CLR + idx] = c * 2;
        }
        if (g < min(prm.cntB[dd * 3 + 1], CAP)) {            // rights (tag 1)
            int c = prm.listR[dd * CAP + g];
            int p = prm.parents[c];
            if ((prm.maskL[p] >> d1) & 1) {                  // only if parent has a left
                int s = prm.firstL[(size_t)dd * NN + p];
                int idx = atomicAdd(&prm.cntCLR[dd * CAP + s], 1);
                if (idx < CLR) prm.childLR[(size_t)(dd * CAP + s) * CLR + idx] = c * 2 + 1;
            }
        }
        if (g < min(prm.cntB[dd * 3 + 2], CAP)) {            // heads: store POSITION g
            int c = prm.listHd[dd * CAP + g];
            int s = prm.firstH[(size_t)dd * NN + prm.parents[c]];
            int idx = atomicAdd(&prm.cntCH[dd * CAP + s], 1);
            if (idx < CH) prm.childH[(size_t)(dd * CAP + s) * CH + idx] = g;
        }
    }
}

// ---------------------------------------------------------------------------
// RR-row 2-layer MLP, 128 threads (thread j = output column j).
// MODE 0 merger: rows=listL, ONLY canonical row g==firstL[p] writes x[p]
// MODE 1 lep:    rows=listHd -> lepOut[g]
// MODE 2 lem:    rows=listHd, ONLY canonical row g==firstH[p] writes x[p]
//                (single-writer: kills the dup-row read/write race on x[p])
template <int MODE, int INDIM>
__device__ void mlpR(const Prm& prm, int d, int g0, int n,
                     const int* __restrict__ rowList,
                     const float* __restrict__ W1, const float* __restrict__ b1,
                     const float* __restrict__ W2, const float* __restrict__ b2,
                     float* sh_raw) {
    const int tid = threadIdx.x;
    float (*sh_in)[INDIM] = (float (*)[INDIM])sh_raw;
    float (*sh_h)[HH]     = (float (*)[HH])(sh_raw + RR * INDIM);
    const int dd = d - 1;
    bool vld[RR];

    if (MODE == 0) {
        #pragma unroll
        for (int r = 0; r < RR; ++r) {
            int g = g0 + r;
            float lv = 0.f, rv = 0.f, pv = 0.f;
            vld[r] = false;
            if (g < n) {
                int p = prm.parents[rowList[g]];
                int s = prm.firstL[(size_t)dd * NN + p];
                vld[r] = (g == s);                       // canonical duplicate only
                lv = prm.left_c [(size_t)s * HH + tid];
                rv = prm.right_c[(size_t)s * HH + tid];
                if (tid < EE) pv = prm.pef[(size_t)p * EE + tid];
            }
            sh_in[r][tid] = lv;
            sh_in[r][HH + tid] = rv;
            if (tid < EE) sh_in[r][2 * HH + tid] = pv;
        }
    } else if (MODE == 2) {
        #pragma unroll
        for (int r = 0; r < RR; ++r) {
            int g = g0 + r;
            float xv = 0.f, mh = 0.f;
            vld[r] = false;
            if (g < n) {
                int p = prm.parents[rowList[g]];
                int s = prm.firstH[(size_t)dd * NN + p];
                vld[r] = (g == s);                       // canonical duplicate only
                xv = prm.x[(size_t)p * HH + tid];
                int cb = dd * CAP + s;
                int cnt = prm.cntCH[cb];
                if (cnt > CH) cnt = CH;
                for (int i = 0; i < cnt; ++i) {
                    int pos = prm.childH[(size_t)cb * CH + i];
                    mh += prm.lepOut[(size_t)pos * HH + tid];
                }
            }
            sh_in[r][tid] = xv;
            sh_in[r][HH + tid] = mh;
        }
    } else {
        #pragma unroll
        for (int r = 0; r < RR; ++r) vld[r] = (g0 + r) < n;
        for (int idx = tid; idx < RR * INDIM; idx += 128) {
            int r = idx / INDIM, k = idx - r * INDIM;
            int g = g0 + r;
            float v = 0.f;
            if (g < n) {
                int c = rowList[g];
                if (k < HH) v = prm.x[(size_t)c * HH + k];
                else        v = prm.plef[(size_t)c * EE + (k - HH)];
            }
            sh_in[r][k] = v;
        }
    }
    __syncthreads();

    float acc[RR];
    #pragma unroll
    for (int r = 0; r < RR; ++r) acc[r] = 0.f;
    for (int kk = 0; kk < INDIM; kk += 4) {
        float w0 = W1[(size_t)(kk + 0) * HH + tid];
        float w1 = W1[(size_t)(kk + 1) * HH + tid];
        float w2 = W1[(size_t)(kk + 2) * HH + tid];
        float w3 = W1[(size_t)(kk + 3) * HH + tid];
        #pragma unroll
        for (int r = 0; r < RR; ++r) {
            float4 v = *(const float4*)&sh_in[r][kk];
            acc[r] += v.x * w0 + v.y * w1 + v.z * w2 + v.w * w3;
        }
    }
    float bb = b1[tid];
    #pragma unroll
    for (int r = 0; r < RR; ++r) sh_h[r][tid] = fmaxf(acc[r] + bb, 0.f);
    __syncthreads();

    float acc2[RR];
    #pragma unroll
    for (int r = 0; r < RR; ++r) acc2[r] = 0.f;
    for (int kk = 0; kk < HH; kk += 4) {
        float w0 = W2[(size_t)(kk + 0) * HH + tid];
        float w1 = W2[(size_t)(kk + 1) * HH + tid];
        float w2 = W2[(size_t)(kk + 2) * HH + tid];
        float w3 = W2[(size_t)(kk + 3) * HH + tid];
        #pragma unroll
        for (int r = 0; r < RR; ++r) {
            float4 v = *(const float4*)&sh_h[r][kk];
            acc2[r] += v.x * w0 + v.y * w1 + v.z * w2 + v.w * w3;
        }
    }
    float bb2 = b2[tid];
    for (int r = 0; r < RR; ++r) {
        int g = g0 + r;
        if (g >= n) break;
        if (!vld[r]) continue;
        float val = acc2[r] + bb2;
        if (MODE == 0) {
            prm.x[(size_t)prm.parents[rowList[g]] * HH + tid] = val;
        } else if (MODE == 1) {
            prm.lepOut[(size_t)g * HH + tid] = val;
        } else {
            int p = prm.parents[rowList[g]];
            if (!((prm.maskL[p] >> d) & 1))        // parents_mask priority
                prm.x[(size_t)p * HH + tid] = val;
        }
    }
}

// ---------------------------------------------------------------------------
// S1 (reads x only): gather left/right child sums [0,G_GATHER) || lep MLP rest
// launch_bounds(128,4): VGPR<=128 -> >=4 waves/SIMD schedulable (R11's 256-VGPR
// allocation collapsed occupancy to 2 waves/SIMD and exposed full L2 latency).
__global__ __launch_bounds__(128, 4)
void s1_kernel(Prm prm, int d) {
    const int dd = d - 1;
    const int bid = blockIdx.x, tid = threadIdx.x;
    if (bid < G_GATHER) {
        int nL = min(prm.cntB[dd * 3 + 0], CAP);
        int w = tid >> 6, lane = tid & 63;
        for (int s = bid * 2 + w; s < nL; s += G_GATHER * 2) {
            int cb = dd * CAP + s;
            int cnt = prm.cntCLR[cb];
            if (cnt > CLR) cnt = CLR;
            float l0 = 0.f, l1 = 0.f, r0 = 0.f, r1 = 0.f;
            for (int i = 0; i < cnt; ++i) {
                int e = prm.childLR[(size_t)cb * CLR + i];
                const float2 v = *(const float2*)(prm.x + (size_t)(e >> 1) * HH + lane * 2);
                if (e & 1) { r0 += v.x; r1 += v.y; } else { l0 += v.x; l1 += v.y; }
            }
            *(float2*)(prm.left_c  + (size_t)s * HH + lane * 2) = make_float2(l0, l1);
            *(float2*)(prm.right_c + (size_t)s * HH + lane * 2) = make_float2(r0, r1);
        }
    } else {
        __shared__ float sh_raw[RR * (HH + EE) + RR * HH];
        int nH = min(prm.cntB[dd * 3 + 2], CAP);
        int g0 = (bid - G_GATHER) * RR;
        if (g0 < nH)
            mlpR<1, HH + EE>(prm, d, g0, nH, prm.listHd + dd * CAP,
                             prm.pW1, prm.pb1, prm.pW2, prm.pb2, sh_raw);
    }
}

// ---------------------------------------------------------------------------
// S2 (writes x): merger [0,CAP/RR) || lem [CAP/RR, 2*CAP/RR).
// Single-writer per x row (canonical dup only); lem's x-read races only on
// rows whose output is discarded.
__global__ __launch_bounds__(128, 4)
void s2_kernel(Prm prm, int d) {
    const int dd = d - 1;
    const int bid = blockIdx.x;
    __shared__ float sh_raw[RR * (2 * HH + EE) + RR * HH];
    if (bid < CAP / RR) {
        int nL = min(prm.cntB[dd * 3 + 0], CAP);
        int g0 = bid * RR;
        if (g0 < nL)
            mlpR<0, 2 * HH + EE>(prm, d, g0, nL, prm.listL + dd * CAP,
                                 prm.mW1, prm.mb1, prm.mW2, prm.mb2, sh_raw);
    } else {
        int nH = min(prm.cntB[dd * 3 + 2], CAP);
        int g0 = (bid - CAP / RR) * RR;
        if (g0 < nH)
            mlpR<2, 2 * HH>(prm, d, g0, nH, prm.listHd + dd * CAP,
                            prm.eW1, prm.eb1, prm.eW2, prm.eb2, sh_raw);
    }
}

// ---------------------------------------------------------------------------
extern "C" void kernel_launch(void* const* d_in, const int* in_sizes, int n_in,
                              void* d_out, int out_size, void* d_ws, size_t ws_size,
                              hipStream_t stream) {
    Prm prm;
    prm.x_in    = (const float*)d_in[0];
    const int* edge = (const int*)d_in[1];
    prm.depths  = (const int*)d_in[2];
    prm.states  = (const int*)d_in[3];
    prm.pef     = (const float*)d_in[4];
    prm.plef    = (const float*)d_in[5];
    prm.mW1 = (const float*)d_in[6];  prm.mb1 = (const float*)d_in[7];
    prm.mW2 = (const float*)d_in[8];  prm.mb2 = (const float*)d_in[9];
    prm.pW1 = (const float*)d_in[10]; prm.pb1 = (const float*)d_in[11];
    prm.pW2 = (const float*)d_in[12]; prm.pb2 = (const float*)d_in[13];
    prm.eW1 = (const float*)d_in[14]; prm.eb1 = (const float*)d_in[15];
    prm.eW2 = (const float*)d_in[16]; prm.eb2 = (const float*)d_in[17];
    prm.x = (float*)d_out;
    prm.parents = edge + NN;

    char* w = (char*)d_ws;
    auto alloc = [&](size_t bytes) {
        void* p = (void*)w;
        w += (bytes + 255) & ~(size_t)255;
        return p;
    };
    // ---- zeroed region ----
    char* zbase = w;
    prm.cntB   = (int*)alloc(64 * 4);
    prm.cntCLR = (int*)alloc((size_t)12 * CAP * 4);
    prm.cntCH  = (int*)alloc((size_t)12 * CAP * 4);
    prm.maskL  = (int*)alloc((size_t)NN * 4);
    prm.maskH  = (int*)alloc((size_t)NN * 4);
    size_t zbytes = (size_t)(w - zbase);
    // ---- 0x7f region (atomicMin init) ----
    char* fbase = w;
    prm.firstL = (int*)alloc((size_t)12 * NN * 4);
    prm.firstH = (int*)alloc((size_t)12 * NN * 4);
    size_t fbytes = (size_t)(w - fbase);
    // ---- non-zeroed (fully rebuilt before use each launch) ----
    prm.listL     = (int*)alloc((size_t)12 * CAP * 4);
    prm.listR     = (int*)alloc((size_t)12 * CAP * 4);
    prm.listHd    = (int*)alloc((size_t)12 * CAP * 4);
    prm.childLR   = (int*)alloc((size_t)12 * CAP * CLR * 4);
    prm.childH    = (int*)alloc((size_t)12 * CAP * CH * 4);
    prm.left_c    = (float*)alloc((size_t)CAP * HH * 4);
    prm.right_c   = (float*)alloc((size_t)CAP * HH * 4);
    prm.lepOut    = (float*)alloc((size_t)CAP * HH * 4);

    hipMemsetAsync(zbase, 0, zbytes, stream);
    hipMemsetAsync(fbase, 0x7f, fbytes, stream);   // firstL/firstH = huge

    copy_x<<<2048, 256, 0, stream>>>((const float4*)prm.x_in, (float4*)prm.x);
    setupA<<<NN / 128, 128, 0, stream>>>(prm);
    setupC<<<384, 256, 0, stream>>>(prm);

    for (int d = MAXD; d >= 1; --d) {
        s1_kernel<<<G_GATHER + CAP / RR, 128, 0, stream>>>(prm, d);
        s2_kernel<<<2 * (CAP / RR), 128, 0, stream>>>(prm, d);
    }
}

// Round 13
// 754.659 us; speedup vs baseline: 2.2577x; 1.3726x over previous
//
#include <hip/hip_runtime.h>

#define NN 262144
#define HH 128
#define EE 16
#define MAXD 12
#define CAP 8192          // per-(depth,category) capacity; expected ~5041
#define CLR 16            // cap: left+right children per slot per depth
#define CH 8              // cap: head children per slot per depth
#define RR 8              // rows per MLP block
#define G_GATHER 320      // S1: blocks [0,G_GATHER) gather (4 workers each), rest lep MLP

struct Prm {
    const float* x_in;
    const int*   parents;
    const int*   depths;
    const int*   states;
    const float* pef;
    const float* plef;
    const float *mW1, *mb1, *mW2, *mb2;
    const float *pW1, *pb1, *pW2, *pb2;
    const float *eW1, *eb1, *eW2, *eb2;
    float* x;
    // zeroed-per-launch:
    int *cntB;            // [36]
    int *cntCLR, *cntCH;  // [12*CAP] each
    int *maskL, *maskH;   // [NN] bit d: has left/head child at depth d
    // memset 0x7f per launch:
    int *firstL, *firstH; // [12*NN] min list-position of p's child (the "slot")
    // rebuilt each launch before use:
    int *listL, *listR, *listHd;       // [12*CAP]
    int *childLR, *childH;             // [12*CAP*CLR], [12*CAP*CH]
    float *left_c, *right_c, *lepOut;  // [CAP*HH]
};

// ---------------------------------------------------------------------------
// x copy through the COMPUTE path (L2-coherent; SDMA memcpy caused R9's stale-
// line failure).
__global__ __launch_bounds__(256)
void copy_x(const float4* __restrict__ src, float4* __restrict__ dst) {
    int i = blockIdx.x * 256 + threadIdx.x;
    const int gsz = 4096 * 256;
    for (; i < NN * HH / 4; i += gsz) dst[i] = src[i];
}

// ---------------------------------------------------------------------------
// setup A: bucket nodes by (depth, cat), build masks, min-position slot
// assignment (scattered atomicMin — no hot counter lines).
__global__ __launch_bounds__(128)
void setupA(Prm prm) {
    __shared__ int lcnt[36], lbase[36];
    const int tid = threadIdx.x;
    const int gtid = blockIdx.x * 128 + tid;       // == node id (2048*128 = NN)

    if (tid < 36) lcnt[tid] = 0;
    __syncthreads();
    int dep = prm.depths[gtid], st = prm.states[gtid];
    int b = -1, rank = 0, p = 0;
    if (dep >= 1 && (st == 0 || st == 1 || st == 3)) {
        int cat = (st == 3) ? 2 : st;
        b = (dep - 1) * 3 + cat;
        rank = atomicAdd(&lcnt[b], 1);
        p = prm.parents[gtid];
        if (cat == 0)      atomicOr(&prm.maskL[p], 1 << dep);
        else if (cat == 2) atomicOr(&prm.maskH[p], 1 << dep);
    }
    __syncthreads();
    if (tid < 36 && lcnt[tid] > 0) lbase[tid] = atomicAdd(&prm.cntB[tid], lcnt[tid]);
    __syncthreads();
    if (b >= 0) {
        int idx = lbase[b] + rank;
        if (idx < CAP) {
            int dd = b / 3, cat = b - dd * 3;
            if (cat == 0) {
                prm.listL[dd * CAP + idx] = gtid;
                atomicMin(&prm.firstL[(size_t)dd * NN + p], idx);   // slot = min pos
            } else if (cat == 1) {
                prm.listR[dd * CAP + idx] = gtid;
            } else {
                prm.listHd[dd * CAP + idx] = gtid;
                atomicMin(&prm.firstH[(size_t)dd * NN + p], idx);
            }
        }
    }
}

// ---------------------------------------------------------------------------
// setup C: append children to per-slot lists (scattered atomics only)
__global__ __launch_bounds__(256)
void setupC(Prm prm) {
    for (int t = blockIdx.x * 256 + threadIdx.x; t < 12 * CAP; t += gridDim.x * 256) {
        int dd = t / CAP, g = t - dd * CAP;
        int d1 = dd + 1;
        if (g < min(prm.cntB[dd * 3 + 0], CAP)) {            // lefts (tag 0)
            int c = prm.listL[dd * CAP + g];
            int s = prm.firstL[(size_t)dd * NN + prm.parents[c]];
            int idx = atomicAdd(&prm.cntCLR[dd * CAP + s], 1);
            if (idx < CLR) prm.childLR[(size_t)(dd * CAP + s) * CLR + idx] = c * 2;
        }
        if (g < min(prm.cntB[dd * 3 + 1], CAP)) {            // rights (tag 1)
            int c = prm.listR[dd * CAP + g];
            int p = prm.parents[c];
            if ((prm.maskL[p] >> d1) & 1) {                  // only if parent has a left
                int s = prm.firstL[(size_t)dd * NN + p];
                int idx = atomicAdd(&prm.cntCLR[dd * CAP + s], 1);
                if (idx < CLR) prm.childLR[(size_t)(dd * CAP + s) * CLR + idx] = c * 2 + 1;
            }
        }
        if (g < min(prm.cntB[dd * 3 + 2], CAP)) {            // heads: store POSITION g
            int c = prm.listHd[dd * CAP + g];
            int s = prm.firstH[(size_t)dd * NN + prm.parents[c]];
            int idx = atomicAdd(&prm.cntCH[dd * CAP + s], 1);
            if (idx < CH) prm.childH[(size_t)(dd * CAP + s) * CH + idx] = g;
        }
    }
}

// ---------------------------------------------------------------------------
// RR-row 2-layer MLP, 256 threads, split-K across halves h=tid>>7 (R2-proven
// shape: batch-8 weight preload wv[8] -> 64 FMAs per batch hides L2 latency).
// MODE 0 merger: rows=listL, ONLY canonical row g==firstL[p] writes x[p]
// MODE 1 lep:    rows=listHd -> lepOut[g]
// MODE 2 lem:    rows=listHd, ONLY canonical row g==firstH[p] writes x[p]
template <int MODE, int INDIM>
__device__ void mlpR(const Prm& prm, int d, int g0, int n,
                     const int* __restrict__ rowList,
                     const float* __restrict__ W1, const float* __restrict__ b1,
                     const float* __restrict__ W2, const float* __restrict__ b2,
                     float* sh_raw) {
    const int tid = threadIdx.x;
    const int h = tid >> 7, j = tid & 127;
    float (*sh_in)[INDIM] = (float (*)[INDIM])sh_raw;
    float (*sh_h)[HH]     = (float (*)[HH])(sh_raw + RR * INDIM);
    float (*sh_pt)[HH]    = (float (*)[HH])(sh_raw + RR * INDIM + RR * HH);
    const int dd = d - 1;

    if (MODE == 0) {
        #pragma unroll
        for (int i = 0; i < RR / 2; ++i) {
            int r = h + 2 * i;                      // each half stages 4 rows
            int g = g0 + r;
            float lv = 0.f, rv = 0.f, pv = 0.f;
            if (g < n) {
                int p = prm.parents[rowList[g]];
                int s = prm.firstL[(size_t)dd * NN + p];
                lv = prm.left_c [(size_t)s * HH + j];
                rv = prm.right_c[(size_t)s * HH + j];
                if (j < EE) pv = prm.pef[(size_t)p * EE + j];
            }
            sh_in[r][j] = lv;
            sh_in[r][HH + j] = rv;
            if (j < EE) sh_in[r][2 * HH + j] = pv;
        }
    } else if (MODE == 2) {
        #pragma unroll
        for (int i = 0; i < RR / 2; ++i) {
            int r = h + 2 * i;
            int g = g0 + r;
            float xv = 0.f, mh = 0.f;
            if (g < n) {
                int p = prm.parents[rowList[g]];
                int s = prm.firstH[(size_t)dd * NN + p];
                xv = prm.x[(size_t)p * HH + j];
                int cb = dd * CAP + s;
                int cnt = prm.cntCH[cb];
                if (cnt > CH) cnt = CH;
                for (int i2 = 0; i2 < cnt; ++i2) {
                    int pos = prm.childH[(size_t)cb * CH + i2];
                    mh += prm.lepOut[(size_t)pos * HH + j];
                }
            }
            sh_in[r][j] = xv;
            sh_in[r][HH + j] = mh;
        }
    } else {
        for (int idx = tid; idx < RR * INDIM; idx += 256) {
            int r = idx / INDIM, k = idx - r * INDIM;
            int g = g0 + r;
            float v = 0.f;
            if (g < n) {
                int c = rowList[g];
                if (k < HH) v = prm.x[(size_t)c * HH + k];
                else        v = prm.plef[(size_t)c * EE + (k - HH)];
            }
            sh_in[r][k] = v;
        }
    }
    __syncthreads();

    constexpr int KH1 = INDIM / 2;
    float acc[RR];
    #pragma unroll
    for (int r = 0; r < RR; ++r) acc[r] = 0.f;
    {
        const float* Wp = W1 + (size_t)h * KH1 * HH + j;
        for (int k = 0; k < KH1; k += 8) {
            float wv[8];
            #pragma unroll
            for (int u = 0; u < 8; ++u) wv[u] = Wp[(size_t)(k + u) * HH];
            #pragma unroll
            for (int u = 0; u < 8; ++u) {
                float w = wv[u];
                int kk = h * KH1 + k + u;
                #pragma unroll
                for (int r = 0; r < RR; ++r) acc[r] += sh_in[r][kk] * w;
            }
        }
    }
    if (h == 1) {
        #pragma unroll
        for (int r = 0; r < RR; ++r) sh_pt[r][j] = acc[r];
    }
    __syncthreads();
    if (h == 0) {
        float bb = b1[j];
        #pragma unroll
        for (int r = 0; r < RR; ++r) sh_h[r][j] = fmaxf(acc[r] + sh_pt[r][j] + bb, 0.f);
    }
    __syncthreads();

    float acc2[RR];
    #pragma unroll
    for (int r = 0; r < RR; ++r) acc2[r] = 0.f;
    {
        const float* Wp = W2 + (size_t)h * (HH / 2) * HH + j;
        for (int k = 0; k < HH / 2; k += 8) {
            float wv[8];
            #pragma unroll
            for (int u = 0; u < 8; ++u) wv[u] = Wp[(size_t)(k + u) * HH];
            #pragma unroll
            for (int u = 0; u < 8; ++u) {
                float w = wv[u];
                int kk = h * (HH / 2) + k + u;
                #pragma unroll
                for (int r = 0; r < RR; ++r) acc2[r] += sh_h[r][kk] * w;
            }
        }
    }
    if (h == 1) {
        #pragma unroll
        for (int r = 0; r < RR; ++r) sh_pt[r][j] = acc2[r];
    }
    __syncthreads();
    if (h == 0) {
        float bb2 = b2[j];
        for (int r = 0; r < RR; ++r) {
            int g = g0 + r;
            if (g >= n) break;
            float val = acc2[r] + sh_pt[r][j] + bb2;
            if (MODE == 1) {
                prm.lepOut[(size_t)g * HH + j] = val;
            } else if (MODE == 0) {
                int p = prm.parents[rowList[g]];
                if (g == prm.firstL[(size_t)dd * NN + p])      // canonical dup only
                    prm.x[(size_t)p * HH + j] = val;
            } else {
                int p = prm.parents[rowList[g]];
                if (g == prm.firstH[(size_t)dd * NN + p] &&    // canonical dup only
                    !((prm.maskL[p] >> d) & 1))                // parents_mask priority
                    prm.x[(size_t)p * HH + j] = val;
            }
        }
    }
}

// ---------------------------------------------------------------------------
// S1 (reads x only): gather left/right child sums [0,G_GATHER) || lep MLP rest
__global__ __launch_bounds__(256, 4)
void s1_kernel(Prm prm, int d) {
    const int dd = d - 1;
    const int bid = blockIdx.x, tid = threadIdx.x;
    if (bid < G_GATHER) {
        int nL = min(prm.cntB[dd * 3 + 0], CAP);
        int w = tid >> 6, lane = tid & 63;
        for (int s = bid * 4 + w; s < nL; s += G_GATHER * 4) {
            int cb = dd * CAP + s;
            int cnt = prm.cntCLR[cb];
            if (cnt > CLR) cnt = CLR;
            float l0 = 0.f, l1 = 0.f, r0 = 0.f, r1 = 0.f;
            for (int i = 0; i < cnt; ++i) {
                int e = prm.childLR[(size_t)cb * CLR + i];
                const float2 v = *(const float2*)(prm.x + (size_t)(e >> 1) * HH + lane * 2);
                if (e & 1) { r0 += v.x; r1 += v.y; } else { l0 += v.x; l1 += v.y; }
            }
            *(float2*)(prm.left_c  + (size_t)s * HH + lane * 2) = make_float2(l0, l1);
            *(float2*)(prm.right_c + (size_t)s * HH + lane * 2) = make_float2(r0, r1);
        }
    } else {
        __shared__ float sh_raw[RR * (HH + EE) + 2 * RR * HH];
        int nH = min(prm.cntB[dd * 3 + 2], CAP);
        int g0 = (bid - G_GATHER) * RR;
        if (g0 < nH)
            mlpR<1, HH + EE>(prm, d, g0, nH, prm.listHd + dd * CAP,
                             prm.pW1, prm.pb1, prm.pW2, prm.pb2, sh_raw);
    }
}

// ---------------------------------------------------------------------------
// S2 (writes x): merger [0,CAP/RR) || lem [CAP/RR, 2*CAP/RR).
// Single-writer per x row (canonical dup only); lem's x-read races only on
// rows whose output is discarded.
__global__ __launch_bounds__(256, 4)
void s2_kernel(Prm prm, int d) {
    const int dd = d - 1;
    const int bid = blockIdx.x;
    __shared__ float sh_raw[RR * (2 * HH + EE) + 2 * RR * HH];
    if (bid < CAP / RR) {
        int nL = min(prm.cntB[dd * 3 + 0], CAP);
        int g0 = bid * RR;
        if (g0 < nL)
            mlpR<0, 2 * HH + EE>(prm, d, g0, nL, prm.listL + dd * CAP,
                                 prm.mW1, prm.mb1, prm.mW2, prm.mb2, sh_raw);
    } else {
        int nH = min(prm.cntB[dd * 3 + 2], CAP);
        int g0 = (bid - CAP / RR) * RR;
        if (g0 < nH)
            mlpR<2, 2 * HH>(prm, d, g0, nH, prm.listHd + dd * CAP,
                            prm.eW1, prm.eb1, prm.eW2, prm.eb2, sh_raw);
    }
}

// ---------------------------------------------------------------------------
extern "C" void kernel_launch(void* const* d_in, const int* in_sizes, int n_in,
                              void* d_out, int out_size, void* d_ws, size_t ws_size,
                              hipStream_t stream) {
    Prm prm;
    prm.x_in    = (const float*)d_in[0];
    const int* edge = (const int*)d_in[1];
    prm.depths  = (const int*)d_in[2];
    prm.states  = (const int*)d_in[3];
    prm.pef     = (const float*)d_in[4];
    prm.plef    = (const float*)d_in[5];
    prm.mW1 = (const float*)d_in[6];  prm.mb1 = (const float*)d_in[7];
    prm.mW2 = (const float*)d_in[8];  prm.mb2 = (const float*)d_in[9];
    prm.pW1 = (const float*)d_in[10]; prm.pb1 = (const float*)d_in[11];
    prm.pW2 = (const float*)d_in[12]; prm.pb2 = (const float*)d_in[13];
    prm.eW1 = (const float*)d_in[14]; prm.eb1 = (const float*)d_in[15];
    prm.eW2 = (const float*)d_in[16]; prm.eb2 = (const float*)d_in[17];
    prm.x = (float*)d_out;
    prm.parents = edge + NN;

    char* w = (char*)d_ws;
    auto alloc = [&](size_t bytes) {
        void* p = (void*)w;
        w += (bytes + 255) & ~(size_t)255;
        return p;
    };
    // ---- zeroed region ----
    char* zbase = w;
    prm.cntB   = (int*)alloc(64 * 4);
    prm.cntCLR = (int*)alloc((size_t)12 * CAP * 4);
    prm.cntCH  = (int*)alloc((size_t)12 * CAP * 4);
    prm.maskL  = (int*)alloc((size_t)NN * 4);
    prm.maskH  = (int*)alloc((size_t)NN * 4);
    size_t zbytes = (size_t)(w - zbase);
    // ---- 0x7f region (atomicMin init) ----
    char* fbase = w;
    prm.firstL = (int*)alloc((size_t)12 * NN * 4);
    prm.firstH = (int*)alloc((size_t)12 * NN * 4);
    size_t fbytes = (size_t)(w - fbase);
    // ---- non-zeroed (fully rebuilt before use each launch) ----
    prm.listL     = (int*)alloc((size_t)12 * CAP * 4);
    prm.listR     = (int*)alloc((size_t)12 * CAP * 4);
    prm.listHd    = (int*)alloc((size_t)12 * CAP * 4);
    prm.childLR   = (int*)alloc((size_t)12 * CAP * CLR * 4);
    prm.childH    = (int*)alloc((size_t)12 * CAP * CH * 4);
    prm.left_c    = (float*)alloc((size_t)CAP * HH * 4);
    prm.right_c   = (float*)alloc((size_t)CAP * HH * 4);
    prm.lepOut    = (float*)alloc((size_t)CAP * HH * 4);

    hipMemsetAsync(zbase, 0, zbytes, stream);
    hipMemsetAsync(fbase, 0x7f, fbytes, stream);   // firstL/firstH = huge

    copy_x<<<4096, 256, 0, stream>>>((const float4*)prm.x_in, (float4*)prm.x);
    setupA<<<NN / 128, 128, 0, stream>>>(prm);
    setupC<<<384, 256, 0, stream>>>(prm);

    for (int d = MAXD; d >= 1; --d) {
        s1_kernel<<<G_GATHER + CAP / RR, 256, 0, stream>>>(prm, d);
        s2_kernel<<<2 * (CAP / RR), 256, 0, stream>>>(prm, d);
    }
}